// Round 12
// baseline (228.805 us; speedup 1.0000x reference)
//
#include <hip/hip_runtime.h>
#include <math.h>

typedef __attribute__((ext_vector_type(4))) float f32x4;
typedef __attribute__((ext_vector_type(8))) int  i32x8;

#define NCLS   50000
#define KSUB   3
#define DIM    512            // elements; fp4 row = 256 B, fp8 row = 512 B
#define NROWSW (NCLS*KSUB)    // 150000
#define BQ     1024

#define SCALEF 30.0f
#define EPSC   1e-7f
#define COSM   0.8775825618903728f
#define SINM   0.4794255386042030f

#define BN     48             // weight rows per tile (lcm(16,3))
#define TW     3              // 16-row MFMA tiles
#define NJ     2              // 16-col B subtiles per wave (32 cols/wave, 256/block)
#define NKQ    4              // K=512 / 128 per scaled MFMA
#define NTILES (NROWSW/BN)    // 3125
#define NRG    128            // row groups
#define NCG    4              // col groups of 256; partners (same rg) share an XCD
#define TILE4B (BN*256)       // 12288 B per LDS buffer (fp4)
#define SCL1   0x7F7F7F7F     // E8M0 scale = 1.0 in every byte

__device__ __forceinline__ float wave_sum(float v) {
#pragma unroll
  for (int m = 1; m < 64; m <<= 1) v += __shfl_xor(v, m, 64);
  return v;
}

__device__ __forceinline__ unsigned pack4_fp8(float a, float b, float c, float d) {
  int v = 0;
  v = __builtin_amdgcn_cvt_pk_fp8_f32(a, b, v, false);
  v = __builtin_amdgcn_cvt_pk_fp8_f32(c, d, v, true);
  return (unsigned)v;
}

__device__ __forceinline__ float eterm(float v) {
  v = fminf(fmaxf(v, -1.f + EPSC), 1.f - EPSC);
  return __expf(SCALEF * v);
}

// nearest e2m1 nibble: values {0,.5,1,1.5,2,3,4,6}; patterns 0..7 in that order
__device__ __forceinline__ unsigned enc_e2m1(float x) {
  unsigned s = (__float_as_uint(x) >> 31) << 3;
  float v = fabsf(x);
  unsigned m;
  if      (v < 0.25f) m = 0;
  else if (v < 0.75f) m = 1;
  else if (v < 1.25f) m = 2;
  else if (v < 1.75f) m = 3;
  else if (v < 2.5f)  m = 4;
  else if (v < 3.5f)  m = 5;
  else if (v < 5.0f)  m = 6;
  else                m = 7;
  return s | m;
}

// K-pre: normalize rows AND MX-fp4 quantize. Per 32-elem block (lanes 4b..4b+3):
// scale 2^sg with sg = ceil(log2(blockmax/6)); nibbles = RNE e2m1 of w*inv*2^-sg.
// Outputs: Wn4 [row][256 B] nibble-packed, sigw [row][4 words] E8M0 bytes
// (word kq, byte j = scale of K-block kq*4+j).
__global__ __launch_bounds__(256) void k_prenorm(const float* __restrict__ W,
                                                 unsigned char* __restrict__ Wn4,
                                                 unsigned* __restrict__ sigw) {
  const int row = blockIdx.x * 4 + (threadIdx.x >> 6);
  const int l = threadIdx.x & 63;
  const float4* p = reinterpret_cast<const float4*>(W + (size_t)row * DIM + l * 8);
  float4 a = p[0], d = p[1];
  float ss = a.x*a.x + a.y*a.y + a.z*a.z + a.w*a.w
           + d.x*d.x + d.y*d.y + d.z*d.z + d.w*d.w;
  ss = wave_sum(ss);
  const float inv = rsqrtf(ss);

  float am = fmaxf(fmaxf(fmaxf(fabsf(a.x), fabsf(a.y)), fmaxf(fabsf(a.z), fabsf(a.w))),
                   fmaxf(fmaxf(fabsf(d.x), fabsf(d.y)), fmaxf(fabsf(d.z), fabsf(d.w)))) * inv;
  am = fmaxf(am, __shfl_xor(am, 1, 64));     // 32-elem block = 4 lanes
  am = fmaxf(am, __shfl_xor(am, 2, 64));

  const float t6 = am * (1.0f / 6.0f);
  const unsigned ut = __float_as_uint(t6);
  int sg = (int)((ut >> 23) & 255) - 127 + ((ut & 0x7fffffu) ? 1 : 0);
  if (!(am > 0.f)) sg = -100;
  sg = sg < -100 ? -100 : (sg > 100 ? 100 : sg);
  const float f = inv * __uint_as_float((unsigned)(127 - sg) << 23);  // inv * 2^-sg

  unsigned pk =  enc_e2m1(a.x * f)        | (enc_e2m1(a.y * f) << 4)
              | (enc_e2m1(a.z * f) << 8)  | (enc_e2m1(a.w * f) << 12)
              | (enc_e2m1(d.x * f) << 16) | (enc_e2m1(d.y * f) << 20)
              | (enc_e2m1(d.z * f) << 24) | (enc_e2m1(d.w * f) << 28);
  *reinterpret_cast<unsigned*>(Wn4 + (size_t)row * 256 + l * 4) = pk;

  const unsigned bv = (unsigned)(127 + sg) & 0xffu;
  const int base = l & 48;
  const unsigned bA = __shfl(bv, base + 0, 64);
  const unsigned bB = __shfl(bv, base + 4, 64);
  const unsigned bC = __shfl(bv, base + 8, 64);
  const unsigned bD = __shfl(bv, base + 12, 64);
  if ((l & 15) == 0)
    sigw[(size_t)row * 4 + (l >> 4)] = bA | (bB << 8) | (bC << 16) | (bD << 24);
}

// K-prep: normalize embeddings -> fp8 En8 AND exact f32 target-class margin terms
__global__ __launch_bounds__(64) void k_prep(const float* __restrict__ E,
                                             const int* __restrict__ lab,
                                             const float* __restrict__ W,
                                             unsigned char* __restrict__ En8,
                                             float* __restrict__ delta,
                                             float* __restrict__ tl) {
  const int b = blockIdx.x, l = threadIdx.x;
  const float4* pe = reinterpret_cast<const float4*>(E + (size_t)b * DIM + l * 8);
  float4 e0 = pe[0], e1 = pe[1];
  float es = e0.x*e0.x + e0.y*e0.y + e0.z*e0.z + e0.w*e0.w
           + e1.x*e1.x + e1.y*e1.y + e1.z*e1.z + e1.w*e1.w;
  es = wave_sum(es);
  const float inv = rsqrtf(es);
  uint2 o;
  o.x = pack4_fp8(e0.x*inv, e0.y*inv, e0.z*inv, e0.w*inv);
  o.y = pack4_fp8(e1.x*inv, e1.y*inv, e1.z*inv, e1.w*inv);
  *reinterpret_cast<uint2*>(En8 + (size_t)b * DIM + l * 8) = o;

  const int L = lab[b];
  float mx = -2.f;
#pragma unroll
  for (int k = 0; k < KSUB; ++k) {
    const float4* pw = reinterpret_cast<const float4*>(W + (size_t)(L * KSUB + k) * DIM + l * 8);
    float4 w0 = pw[0], w1 = pw[1];
    float ds = e0.x*w0.x + e0.y*w0.y + e0.z*w0.z + e0.w*w0.w
             + e1.x*w1.x + e1.y*w1.y + e1.z*w1.z + e1.w*w1.w;
    float ws = w0.x*w0.x + w0.y*w0.y + w0.z*w0.z + w0.w*w0.w
             + w1.x*w1.x + w1.y*w1.y + w1.z*w1.z + w1.w*w1.w;
    ds = wave_sum(ds);
    ws = wave_sum(ws);
    float ck = ds * rsqrtf(es * ws);
    mx = fmaxf(mx, ck);
  }
  if (l == 0) {
    float cc = fminf(fmaxf(mx, -1.f + EPSC), 1.f - EPSC);
    float sn = sqrtf(fmaxf(1.f - cc * cc, 0.f));
    float mg = cc * COSM - sn * SINM;           // cos(arccos(cc)+m)
    delta[b] = __expf(SCALEF * mg) - __expf(SCALEF * cc);
    tl[b]    = SCALEF * mg;
  }
}

// stage one 48-row fp4 tile (12 KB) via global_load_lds; 12 wave-issues.
// LDS slot s of row r holds global chunk s ^ (r&15) (involution; read XORs same).
__device__ __forceinline__ void stage4(const unsigned char* __restrict__ Wt,
                                       unsigned char* lbuf, int wv, int lane) {
  {
    const int r = wv * 4 + (lane >> 4);
    const int m = (lane & 15) ^ (r & 15);
    __builtin_amdgcn_global_load_lds(
        (const __attribute__((address_space(1))) unsigned int*)(Wt + (size_t)r * 256 + m * 16),
        (__attribute__((address_space(3))) unsigned int*)(lbuf + wv * 1024),
        16, 0, 0);
  }
  if (wv < 4) {
    const int r = 32 + wv * 4 + (lane >> 4);
    const int m = (lane & 15) ^ (r & 15);
    __builtin_amdgcn_global_load_lds(
        (const __attribute__((address_space(1))) unsigned int*)(Wt + (size_t)r * 256 + m * 16),
        (__attribute__((address_space(3))) unsigned int*)(lbuf + (8 + wv) * 1024),
        16, 0, 0);
  }
}

// K1: mixed MX MFMA — A = W fp4 (cbsz=4, per-lane block scales), B = E fp8
// (scale 1.0). E-fragments in registers (64 VGPR, loaded once); W in dbuf LDS
// (2x12 KB). 12 ds_read_b128 per wave-tile. Epilogue identical to verified R9.
__global__ __launch_bounds__(512, 4) void k_main(const unsigned char* __restrict__ Wn4,
                                                 const unsigned* __restrict__ sigw,
                                                 const unsigned char* __restrict__ En8,
                                                 float* __restrict__ Zp) {
  __shared__ __align__(16) unsigned char wlds[2 * TILE4B];   // 24 KB
  const int tid  = threadIdx.x;
  const int lane = tid & 63;
  const int wv   = tid >> 6;
  const int g    = lane >> 4;
  const int c    = lane & 15;
  const int rg   = blockIdx.x & (NRG - 1);   // partners share XCD: blk%8 = rg%8
  const int cg   = blockIdx.x >> 7;

  // ---- load this wave's E fragments once: 2 x 4 x i32x8 = 64 VGPRs ----
  i32x8 bfr[NJ][NKQ];
#pragma unroll
  for (int j = 0; j < NJ; ++j) {
    const int col = cg * 256 + wv * 32 + j * 16 + c;
#pragma unroll
    for (int kq = 0; kq < NKQ; ++kq)
      bfr[j][kq] = *reinterpret_cast<const i32x8*>(
          En8 + (size_t)col * DIM + kq * 128 + g * 32);
  }

  float zreg[NJ];
#pragma unroll
  for (int j = 0; j < NJ; ++j) zreg[j] = 0.f;

  stage4(Wn4 + (size_t)rg * TILE4B, wlds, wv, lane);
  __syncthreads();
  int cur = 0;

  for (int tile = rg; tile < NTILES; tile += NRG) {
    const int nxt = tile + NRG;
    if (nxt < NTILES)
      stage4(Wn4 + (size_t)nxt * TILE4B, wlds + (cur ^ 1) * TILE4B, wv, lane);

    const unsigned char* lbuf = wlds + cur * TILE4B;

    f32x4 acc[TW][NJ];
#pragma unroll
    for (int t = 0; t < TW; ++t)
#pragma unroll
      for (int j = 0; j < NJ; ++j) acc[t][j] = (f32x4){0.f, 0.f, 0.f, 0.f};

#pragma unroll
    for (int kq = 0; kq < NKQ; ++kq) {
#pragma unroll
      for (int t = 0; t < TW; ++t) {
        const int r = t * 16 + c;                 // r & 15 == c
        const unsigned swd = sigw[(size_t)(tile * BN + r) * 4 + kq];
        const unsigned sA = ((swd >> (g * 8)) & 0xffu) * 0x01010101u;  // own block, x4
        const int s = (kq * 4 + g) ^ c;
        const int4 v = *reinterpret_cast<const int4*>(lbuf + r * 256 + s * 16);
        i32x8 av = (i32x8){0, 0, 0, 0, 0, 0, 0, 0};
        av[0] = v.x; av[1] = v.y; av[2] = v.z; av[3] = v.w;
#pragma unroll
        for (int j = 0; j < NJ; ++j)
          acc[t][j] = __builtin_amdgcn_mfma_scale_f32_16x16x128_f8f6f4(
              av, bfr[j][kq], acc[t][j], 4, 0, 0, (int)sA, 0, SCL1);
      }
    }

    // ---- epilogue: max over sub-center triples (verified), exp; lane-partials ----
#pragma unroll
    for (int j = 0; j < NJ; ++j) {
      float zc = 0.f;
#pragma unroll
      for (int t = 0; t < TW; ++t) {
        float s0, s1;
        if (t + 1 < TW) {
          s0 = (g == 0) ? acc[t + 1][j][0] : acc[t][j][0];
          s1 = (g == 0) ? acc[t + 1][j][1] : acc[t][j][1];
        } else {
          s0 = (g == 0) ? -2.f : acc[t][j][0];
          s1 = (g == 0) ? -2.f : acc[t][j][1];
        }
        float e0 = __shfl(s0, (lane + 16) & 63, 64);
        float e1 = __shfl(s1, (lane + 16) & 63, 64);
        const int m = (4 * t + g) % 3;
        float a0 = acc[t][j][0], a1 = acc[t][j][1], a2 = acc[t][j][2], a3 = acc[t][j][3];
        if (m == 0)      zc += eterm(fmaxf(fmaxf(a0, a1), a2)) + eterm(fmaxf(fmaxf(a3, e0), e1));
        else if (m == 1) zc += eterm(fmaxf(fmaxf(a2, a3), e0));
        else             zc += eterm(fmaxf(fmaxf(a1, a2), a3));
      }
      zreg[j] += zc;                 // cross-lane reduce ONCE at end
    }

    __syncthreads();   // staging drained + all waves done with cur
    cur ^= 1;
  }

  // ---- final cross-lane reduction ----
#pragma unroll
  for (int j = 0; j < NJ; ++j) {
    zreg[j] += __shfl_xor(zreg[j], 16, 64);
    zreg[j] += __shfl_xor(zreg[j], 32, 64);
  }
  if (g == 0) {
#pragma unroll
    for (int j = 0; j < NJ; ++j)
      Zp[(size_t)rg * BQ + cg * 256 + wv * 32 + j * 16 + c] = zreg[j];
  }
}

// K3: Z[b] = sum over 128 row-group partials; per-row loss; block partial sums
__global__ __launch_bounds__(256) void k_reduce(const float* __restrict__ Zp,
                                                const float* __restrict__ delta,
                                                const float* __restrict__ tl,
                                                float* __restrict__ part) {
  const int b = blockIdx.x * 256 + threadIdx.x;
  float z = 0.f;
#pragma unroll 8
  for (int nb = 0; nb < NRG; ++nb) z += Zp[(size_t)nb * BQ + b];
  float lossb = logf(z + delta[b]) - tl[b];
  __shared__ float sm[256];
  sm[threadIdx.x] = lossb;
  __syncthreads();
#pragma unroll
  for (int s = 128; s > 0; s >>= 1) {
    if (threadIdx.x < s) sm[threadIdx.x] += sm[threadIdx.x + s];
    __syncthreads();
  }
  if (threadIdx.x == 0) part[blockIdx.x] = sm[0];
}

__global__ void k_final(const float* __restrict__ part, float* __restrict__ out) {
  out[0] = (part[0] + part[1] + part[2] + part[3]) * (1.0f / BQ);
}

extern "C" void kernel_launch(void* const* d_in, const int* in_sizes, int n_in,
                              void* d_out, int out_size, void* d_ws, size_t ws_size,
                              hipStream_t stream) {
  const float* E  = (const float*)d_in[0];
  const int* lab  = (const int*)d_in[1];
  const float* W  = (const float*)d_in[2];

  char* ws = (char*)d_ws;
  unsigned char* En8 = (unsigned char*)ws;                            // 512 KB
  unsigned char* Wn4 = (unsigned char*)(ws + (size_t)BQ * DIM);       // 38.4 MB
  unsigned* sigw = (unsigned*)(ws + (size_t)BQ * DIM + (size_t)NROWSW * 256);  // 2.4 MB
  char* after = (char*)(sigw + (size_t)NROWSW * 4);
  float* Zp    = (float*)after;                                       // 512 KB
  float* delta = Zp + (size_t)NRG * BQ;
  float* tl    = delta + BQ;
  float* part  = tl + BQ;

  hipLaunchKernelGGL(k_prenorm, dim3(NROWSW / 4), dim3(256), 0, stream, W, Wn4, sigw);
  hipLaunchKernelGGL(k_prep,    dim3(BQ),         dim3(64),  0, stream, E, lab, W, En8, delta, tl);
  hipLaunchKernelGGL(k_main,    dim3(NRG * NCG),  dim3(512), 0, stream, Wn4, sigw, En8, Zp);
  hipLaunchKernelGGL(k_reduce,  dim3(4),          dim3(256), 0, stream, Zp, delta, tl, part);
  hipLaunchKernelGGL(k_final,   dim3(1),          dim3(1),   0, stream, part, (float*)d_out);
}

// Round 13
// 163.695 us; speedup vs baseline: 1.3977x; 1.3977x over previous
//
#include <hip/hip_runtime.h>
#include <math.h>

typedef __attribute__((ext_vector_type(4))) float f32x4;
typedef __attribute__((ext_vector_type(8))) int  i32x8;

#define NCLS   50000
#define KSUB   3
#define DIM    512            // elements; fp4 row = 256 B, fp8 row = 512 B
#define NROWSW (NCLS*KSUB)    // 150000
#define BQ     1024

#define SCALEF 30.0f
#define EPSC   1e-7f
#define COSM   0.8775825618903728f
#define SINM   0.4794255386042030f

#define BN     48             // weight rows per tile (lcm(16,3))
#define TW     3              // 16-row MFMA tiles
#define NJ     2              // 16-col B subtiles per wave (32 cols/wave, 256/block)
#define NKQ    4              // K=512 / 128 per scaled MFMA
#define NTILES (NROWSW/BN)    // 3125
#define NRG    128            // row groups
#define NCG    4              // col groups of 256; partners (same rg) share an XCD
#define TILE4B (BN*256)       // 12288 B tile data (fp4)
#define TILESB (TILE4B+1024)  // + 768 B scales (padded to 1 KB) per LDS buffer
#define SCL1   0x7F7F7F7F     // E8M0 scale = 1.0 in every byte

__device__ __forceinline__ float wave_sum(float v) {
#pragma unroll
  for (int m = 1; m < 64; m <<= 1) v += __shfl_xor(v, m, 64);
  return v;
}

__device__ __forceinline__ unsigned pack4_fp8(float a, float b, float c, float d) {
  int v = 0;
  v = __builtin_amdgcn_cvt_pk_fp8_f32(a, b, v, false);
  v = __builtin_amdgcn_cvt_pk_fp8_f32(c, d, v, true);
  return (unsigned)v;
}

__device__ __forceinline__ float eterm(float v) {
  v = fminf(fmaxf(v, -1.f + EPSC), 1.f - EPSC);
  return __expf(SCALEF * v);
}

// nearest e2m1 nibble: values {0,.5,1,1.5,2,3,4,6}; patterns 0..7 in that order
__device__ __forceinline__ unsigned enc_e2m1(float x) {
  unsigned s = (__float_as_uint(x) >> 31) << 3;
  float v = fabsf(x);
  unsigned m;
  if      (v < 0.25f) m = 0;
  else if (v < 0.75f) m = 1;
  else if (v < 1.25f) m = 2;
  else if (v < 1.75f) m = 3;
  else if (v < 2.5f)  m = 4;
  else if (v < 3.5f)  m = 5;
  else if (v < 5.0f)  m = 6;
  else                m = 7;
  return s | m;
}

// K-pre: normalize rows AND MX-fp4 quantize (validated in R12).
// Outputs: Wn4 [row][256 B] nibble-packed; sigw [row][4 words] E8M0 bytes
// (word kq, byte j = scale of K-block kq*4+j).
__global__ __launch_bounds__(256) void k_prenorm(const float* __restrict__ W,
                                                 unsigned char* __restrict__ Wn4,
                                                 unsigned* __restrict__ sigw) {
  const int row = blockIdx.x * 4 + (threadIdx.x >> 6);
  const int l = threadIdx.x & 63;
  const float4* p = reinterpret_cast<const float4*>(W + (size_t)row * DIM + l * 8);
  float4 a = p[0], d = p[1];
  float ss = a.x*a.x + a.y*a.y + a.z*a.z + a.w*a.w
           + d.x*d.x + d.y*d.y + d.z*d.z + d.w*d.w;
  ss = wave_sum(ss);
  const float inv = rsqrtf(ss);

  float am = fmaxf(fmaxf(fmaxf(fabsf(a.x), fabsf(a.y)), fmaxf(fabsf(a.z), fabsf(a.w))),
                   fmaxf(fmaxf(fabsf(d.x), fabsf(d.y)), fmaxf(fabsf(d.z), fabsf(d.w)))) * inv;
  am = fmaxf(am, __shfl_xor(am, 1, 64));     // 32-elem block = 4 lanes
  am = fmaxf(am, __shfl_xor(am, 2, 64));

  const float t6 = am * (1.0f / 6.0f);
  const unsigned ut = __float_as_uint(t6);
  int sg = (int)((ut >> 23) & 255) - 127 + ((ut & 0x7fffffu) ? 1 : 0);
  if (!(am > 0.f)) sg = -100;
  sg = sg < -100 ? -100 : (sg > 100 ? 100 : sg);
  const float f = inv * __uint_as_float((unsigned)(127 - sg) << 23);  // inv * 2^-sg

  unsigned pk =  enc_e2m1(a.x * f)        | (enc_e2m1(a.y * f) << 4)
              | (enc_e2m1(a.z * f) << 8)  | (enc_e2m1(a.w * f) << 12)
              | (enc_e2m1(d.x * f) << 16) | (enc_e2m1(d.y * f) << 20)
              | (enc_e2m1(d.z * f) << 24) | (enc_e2m1(d.w * f) << 28);
  *reinterpret_cast<unsigned*>(Wn4 + (size_t)row * 256 + l * 4) = pk;

  const unsigned bv = (unsigned)(127 + sg) & 0xffu;
  const int base = l & 48;
  const unsigned bA = __shfl(bv, base + 0, 64);
  const unsigned bB = __shfl(bv, base + 4, 64);
  const unsigned bC = __shfl(bv, base + 8, 64);
  const unsigned bD = __shfl(bv, base + 12, 64);
  if ((l & 15) == 0)
    sigw[(size_t)row * 4 + (l >> 4)] = bA | (bB << 8) | (bC << 16) | (bD << 24);
}

// K-prep: normalize embeddings -> fp8 En8 AND exact f32 target-class margin terms
__global__ __launch_bounds__(64) void k_prep(const float* __restrict__ E,
                                             const int* __restrict__ lab,
                                             const float* __restrict__ W,
                                             unsigned char* __restrict__ En8,
                                             float* __restrict__ delta,
                                             float* __restrict__ tl) {
  const int b = blockIdx.x, l = threadIdx.x;
  const float4* pe = reinterpret_cast<const float4*>(E + (size_t)b * DIM + l * 8);
  float4 e0 = pe[0], e1 = pe[1];
  float es = e0.x*e0.x + e0.y*e0.y + e0.z*e0.z + e0.w*e0.w
           + e1.x*e1.x + e1.y*e1.y + e1.z*e1.z + e1.w*e1.w;
  es = wave_sum(es);
  const float inv = rsqrtf(es);
  uint2 o;
  o.x = pack4_fp8(e0.x*inv, e0.y*inv, e0.z*inv, e0.w*inv);
  o.y = pack4_fp8(e1.x*inv, e1.y*inv, e1.z*inv, e1.w*inv);
  *reinterpret_cast<uint2*>(En8 + (size_t)b * DIM + l * 8) = o;

  const int L = lab[b];
  float mx = -2.f;
#pragma unroll
  for (int k = 0; k < KSUB; ++k) {
    const float4* pw = reinterpret_cast<const float4*>(W + (size_t)(L * KSUB + k) * DIM + l * 8);
    float4 w0 = pw[0], w1 = pw[1];
    float ds = e0.x*w0.x + e0.y*w0.y + e0.z*w0.z + e0.w*w0.w
             + e1.x*w1.x + e1.y*w1.y + e1.z*w1.z + e1.w*w1.w;
    float ws = w0.x*w0.x + w0.y*w0.y + w0.z*w0.z + w0.w*w0.w
             + w1.x*w1.x + w1.y*w1.y + w1.z*w1.z + w1.w*w1.w;
    ds = wave_sum(ds);
    ws = wave_sum(ws);
    float ck = ds * rsqrtf(es * ws);
    mx = fmaxf(mx, ck);
  }
  if (l == 0) {
    float cc = fminf(fmaxf(mx, -1.f + EPSC), 1.f - EPSC);
    float sn = sqrtf(fmaxf(1.f - cc * cc, 0.f));
    float mg = cc * COSM - sn * SINM;           // cos(arccos(cc)+m)
    delta[b] = __expf(SCALEF * mg) - __expf(SCALEF * cc);
    tl[b]    = SCALEF * mg;
  }
}

// stage one 48-row fp4 tile (12 KB) AND its 768 B scale block via global_load_lds.
// Tile: LDS slot s of row r holds global chunk s ^ (r&15) (involution).
// Scales: linear at lbuf+12288 (row r's uint4 at +r*16), staged by wave 4.
__device__ __forceinline__ void stage4(const unsigned char* __restrict__ Wt,
                                       const unsigned char* __restrict__ sgt,
                                       unsigned char* lbuf, int wv, int lane) {
  {
    const int r = wv * 4 + (lane >> 4);
    const int m = (lane & 15) ^ (r & 15);
    __builtin_amdgcn_global_load_lds(
        (const __attribute__((address_space(1))) unsigned int*)(Wt + (size_t)r * 256 + m * 16),
        (__attribute__((address_space(3))) unsigned int*)(lbuf + wv * 1024),
        16, 0, 0);
  }
  if (wv < 4) {
    const int r = 32 + wv * 4 + (lane >> 4);
    const int m = (lane & 15) ^ (r & 15);
    __builtin_amdgcn_global_load_lds(
        (const __attribute__((address_space(1))) unsigned int*)(Wt + (size_t)r * 256 + m * 16),
        (__attribute__((address_space(3))) unsigned int*)(lbuf + (8 + wv) * 1024),
        16, 0, 0);
  } else if (wv == 4 && lane < 48) {
    __builtin_amdgcn_global_load_lds(
        (const __attribute__((address_space(1))) unsigned int*)(sgt + lane * 16),
        (__attribute__((address_space(3))) unsigned int*)(lbuf + TILE4B),
        16, 0, 0);
  }
}

// K1: mixed MX MFMA — A = W fp4 (cbsz=4, per-block scales from LDS), B = E fp8
// (scale 1.0). E-fragments in registers (64 VGPR); W+scales in dbuf LDS via
// global_load_lds (prefetch dist 1). 12+3 ds_read_b128 per wave-tile.
__global__ __launch_bounds__(512, 4) void k_main(const unsigned char* __restrict__ Wn4,
                                                 const unsigned char* __restrict__ sigw,
                                                 const unsigned char* __restrict__ En8,
                                                 float* __restrict__ Zp) {
  __shared__ __align__(16) unsigned char wlds[2 * TILESB];   // 26 KB
  const int tid  = threadIdx.x;
  const int lane = tid & 63;
  const int wv   = tid >> 6;
  const int g    = lane >> 4;
  const int c    = lane & 15;
  const int rg   = blockIdx.x & (NRG - 1);   // partners share XCD: blk%8 = rg%8
  const int cg   = blockIdx.x >> 7;

  // ---- load this wave's E fragments once: 2 x 4 x i32x8 = 64 VGPRs ----
  i32x8 bfr[NJ][NKQ];
#pragma unroll
  for (int j = 0; j < NJ; ++j) {
    const int col = cg * 256 + wv * 32 + j * 16 + c;
#pragma unroll
    for (int kq = 0; kq < NKQ; ++kq)
      bfr[j][kq] = *reinterpret_cast<const i32x8*>(
          En8 + (size_t)col * DIM + kq * 128 + g * 32);
  }

  float zreg[NJ];
#pragma unroll
  for (int j = 0; j < NJ; ++j) zreg[j] = 0.f;

  stage4(Wn4 + (size_t)rg * TILE4B, sigw + (size_t)rg * 768, wlds, wv, lane);
  __syncthreads();
  int cur = 0;

  for (int tile = rg; tile < NTILES; tile += NRG) {
    const int nxt = tile + NRG;
    if (nxt < NTILES)
      stage4(Wn4 + (size_t)nxt * TILE4B, sigw + (size_t)nxt * 768,
             wlds + (cur ^ 1) * TILESB, wv, lane);

    const unsigned char* lbuf = wlds + cur * TILESB;

    // per-t scale words for this lane's rows (r = t*16+c): 3 x ds_read_b128
    uint4 sgv[TW];
#pragma unroll
    for (int t = 0; t < TW; ++t)
      sgv[t] = *reinterpret_cast<const uint4*>(lbuf + TILE4B + (t * 16 + c) * 16);

    f32x4 acc[TW][NJ];
#pragma unroll
    for (int t = 0; t < TW; ++t)
#pragma unroll
      for (int j = 0; j < NJ; ++j) acc[t][j] = (f32x4){0.f, 0.f, 0.f, 0.f};

#pragma unroll
    for (int kq = 0; kq < NKQ; ++kq) {
#pragma unroll
      for (int t = 0; t < TW; ++t) {
        const int r = t * 16 + c;                 // r & 15 == c
        const unsigned swd = (&sgv[t].x)[kq];     // static after unroll
        const unsigned sA = ((swd >> (g * 8)) & 0xffu) * 0x01010101u;
        const int s = (kq * 4 + g) ^ c;
        const int4 v = *reinterpret_cast<const int4*>(lbuf + r * 256 + s * 16);
        i32x8 av = (i32x8){0, 0, 0, 0, 0, 0, 0, 0};
        av[0] = v.x; av[1] = v.y; av[2] = v.z; av[3] = v.w;
#pragma unroll
        for (int j = 0; j < NJ; ++j)
          acc[t][j] = __builtin_amdgcn_mfma_scale_f32_16x16x128_f8f6f4(
              av, bfr[j][kq], acc[t][j], 4, 0, 0, (int)sA, 0, SCL1);
      }
    }

    // ---- epilogue: max over sub-center triples (verified), exp; lane-partials ----
#pragma unroll
    for (int j = 0; j < NJ; ++j) {
      float zc = 0.f;
#pragma unroll
      for (int t = 0; t < TW; ++t) {
        float s0, s1;
        if (t + 1 < TW) {
          s0 = (g == 0) ? acc[t + 1][j][0] : acc[t][j][0];
          s1 = (g == 0) ? acc[t + 1][j][1] : acc[t][j][1];
        } else {
          s0 = (g == 0) ? -2.f : acc[t][j][0];
          s1 = (g == 0) ? -2.f : acc[t][j][1];
        }
        float e0 = __shfl(s0, (lane + 16) & 63, 64);
        float e1 = __shfl(s1, (lane + 16) & 63, 64);
        const int m = (4 * t + g) % 3;
        float a0 = acc[t][j][0], a1 = acc[t][j][1], a2 = acc[t][j][2], a3 = acc[t][j][3];
        if (m == 0)      zc += eterm(fmaxf(fmaxf(a0, a1), a2)) + eterm(fmaxf(fmaxf(a3, e0), e1));
        else if (m == 1) zc += eterm(fmaxf(fmaxf(a2, a3), e0));
        else             zc += eterm(fmaxf(fmaxf(a1, a2), a3));
      }
      zreg[j] += zc;                 // cross-lane reduce ONCE at end
    }

    __syncthreads();   // staging drained + all waves done with cur
    cur ^= 1;
  }

  // ---- final cross-lane reduction ----
#pragma unroll
  for (int j = 0; j < NJ; ++j) {
    zreg[j] += __shfl_xor(zreg[j], 16, 64);
    zreg[j] += __shfl_xor(zreg[j], 32, 64);
  }
  if (g == 0) {
#pragma unroll
    for (int j = 0; j < NJ; ++j)
      Zp[(size_t)rg * BQ + cg * 256 + wv * 32 + j * 16 + c] = zreg[j];
  }
}

// K3: Z[b] = sum over 128 row-group partials; per-row loss; block partial sums
__global__ __launch_bounds__(256) void k_reduce(const float* __restrict__ Zp,
                                                const float* __restrict__ delta,
                                                const float* __restrict__ tl,
                                                float* __restrict__ part) {
  const int b = blockIdx.x * 256 + threadIdx.x;
  float z = 0.f;
#pragma unroll 8
  for (int nb = 0; nb < NRG; ++nb) z += Zp[(size_t)nb * BQ + b];
  float lossb = logf(z + delta[b]) - tl[b];
  __shared__ float sm[256];
  sm[threadIdx.x] = lossb;
  __syncthreads();
#pragma unroll
  for (int s = 128; s > 0; s >>= 1) {
    if (threadIdx.x < s) sm[threadIdx.x] += sm[threadIdx.x + s];
    __syncthreads();
  }
  if (threadIdx.x == 0) part[blockIdx.x] = sm[0];
}

__global__ void k_final(const float* __restrict__ part, float* __restrict__ out) {
  out[0] = (part[0] + part[1] + part[2] + part[3]) * (1.0f / BQ);
}

extern "C" void kernel_launch(void* const* d_in, const int* in_sizes, int n_in,
                              void* d_out, int out_size, void* d_ws, size_t ws_size,
                              hipStream_t stream) {
  const float* E  = (const float*)d_in[0];
  const int* lab  = (const int*)d_in[1];
  const float* W  = (const float*)d_in[2];

  char* ws = (char*)d_ws;
  unsigned char* En8 = (unsigned char*)ws;                            // 512 KB
  unsigned char* Wn4 = (unsigned char*)(ws + (size_t)BQ * DIM);       // 38.4 MB
  unsigned* sigw = (unsigned*)(ws + (size_t)BQ * DIM + (size_t)NROWSW * 256);  // 2.4 MB
  char* after = (char*)(sigw + (size_t)NROWSW * 4);
  float* Zp    = (float*)after;                                       // 512 KB
  float* delta = Zp + (size_t)NRG * BQ;
  float* tl    = delta + BQ;
  float* part  = tl + BQ;

  hipLaunchKernelGGL(k_prenorm, dim3(NROWSW / 4), dim3(256), 0, stream, W, Wn4, sigw);
  hipLaunchKernelGGL(k_prep,    dim3(BQ),         dim3(64),  0, stream, E, lab, W, En8, delta, tl);
  hipLaunchKernelGGL(k_main,    dim3(NRG * NCG),  dim3(512), 0, stream, Wn4, (unsigned char*)sigw, En8, Zp);
  hipLaunchKernelGGL(k_reduce,  dim3(4),          dim3(256), 0, stream, Zp, delta, tl, part);
  hipLaunchKernelGGL(k_final,   dim3(1),          dim3(1),   0, stream, part, (float*)d_out);
}

// Round 14
// 140.694 us; speedup vs baseline: 1.6263x; 1.1635x over previous
//
#include <hip/hip_runtime.h>
#include <math.h>

typedef __attribute__((ext_vector_type(4))) float f32x4;
typedef __attribute__((ext_vector_type(8))) int  i32x8;

#define NCLS   50000
#define KSUB   3
#define DIM    512            // elements; fp4 row = 256 B, fp8 row = 512 B
#define NROWSW (NCLS*KSUB)    // 150000
#define BQ     1024

#define SCALEF 30.0f
#define EPSC   1e-7f
#define COSM   0.8775825618903728f
#define SINM   0.4794255386042030f

#define BN     48             // weight rows per tile (lcm(16,3))
#define TW     3              // 16-row MFMA tiles = 3 sub-centers after permutation
#define NJ     2              // 16-col B subtiles per wave (32 cols/wave, 256/block)
#define NKQ    4              // K=512 / 128 per scaled MFMA
#define NTILES (NROWSW/BN)    // 3125
#define NRG    128            // row groups
#define NCG    4              // col groups of 256; partners (same rg) share an XCD
#define TILE4B (BN*256)       // 12288 B tile data (fp4)
#define TILESB (TILE4B+1024)  // + 768 B scales (padded to 1 KB) per LDS buffer
#define SCL1   0x7F7F7F7F     // E8M0 scale = 1.0 in every byte

__device__ __forceinline__ float wave_sum(float v) {
#pragma unroll
  for (int m = 1; m < 64; m <<= 1) v += __shfl_xor(v, m, 64);
  return v;
}

__device__ __forceinline__ unsigned pack4_fp8(float a, float b, float c, float d) {
  int v = 0;
  v = __builtin_amdgcn_cvt_pk_fp8_f32(a, b, v, false);
  v = __builtin_amdgcn_cvt_pk_fp8_f32(c, d, v, true);
  return (unsigned)v;
}

__device__ __forceinline__ float eterm(float v) {
  v = fminf(fmaxf(v, -1.f + EPSC), 1.f - EPSC);
  return __expf(SCALEF * v);
}

// nearest e2m1 nibble: values {0,.5,1,1.5,2,3,4,6}; patterns 0..7 in that order
__device__ __forceinline__ unsigned enc_e2m1(float x) {
  unsigned s = (__float_as_uint(x) >> 31) << 3;
  float v = fabsf(x);
  unsigned m;
  if      (v < 0.25f) m = 0;
  else if (v < 0.75f) m = 1;
  else if (v < 1.25f) m = 2;
  else if (v < 1.75f) m = 3;
  else if (v < 2.5f)  m = 4;
  else if (v < 3.5f)  m = 5;
  else if (v < 5.0f)  m = 6;
  else                m = 7;
  return s | m;
}

// K-pre: normalize rows AND MX-fp4 quantize (validated R12/R13), writing rows
// PERMUTED within each 48-row tile: orig row 3q+k (class q, sub-center k)
// -> tile-row q + 16k. MFMA tile t then holds sub-center t of all 16 classes,
// so the 3 sub-centers of a class land in the SAME lane+reg of acc[0..2].
__global__ __launch_bounds__(256) void k_prenorm(const float* __restrict__ W,
                                                 unsigned char* __restrict__ Wn4,
                                                 unsigned* __restrict__ sigw) {
  const int row = blockIdx.x * 4 + (threadIdx.x >> 6);
  const int l = threadIdx.x & 63;
  const int tile = row / BN;
  const int rr   = row - tile * BN;
  const int outr = tile * BN + rr / 3 + 16 * (rr % 3);   // permuted destination row

  const float4* p = reinterpret_cast<const float4*>(W + (size_t)row * DIM + l * 8);
  float4 a = p[0], d = p[1];
  float ss = a.x*a.x + a.y*a.y + a.z*a.z + a.w*a.w
           + d.x*d.x + d.y*d.y + d.z*d.z + d.w*d.w;
  ss = wave_sum(ss);
  const float inv = rsqrtf(ss);

  float am = fmaxf(fmaxf(fmaxf(fabsf(a.x), fabsf(a.y)), fmaxf(fabsf(a.z), fabsf(a.w))),
                   fmaxf(fmaxf(fabsf(d.x), fabsf(d.y)), fmaxf(fabsf(d.z), fabsf(d.w)))) * inv;
  am = fmaxf(am, __shfl_xor(am, 1, 64));     // 32-elem block = 4 lanes
  am = fmaxf(am, __shfl_xor(am, 2, 64));

  const float t6 = am * (1.0f / 6.0f);
  const unsigned ut = __float_as_uint(t6);
  int sg = (int)((ut >> 23) & 255) - 127 + ((ut & 0x7fffffu) ? 1 : 0);
  if (!(am > 0.f)) sg = -100;
  sg = sg < -100 ? -100 : (sg > 100 ? 100 : sg);
  const float f = inv * __uint_as_float((unsigned)(127 - sg) << 23);  // inv * 2^-sg

  unsigned pk =  enc_e2m1(a.x * f)        | (enc_e2m1(a.y * f) << 4)
              | (enc_e2m1(a.z * f) << 8)  | (enc_e2m1(a.w * f) << 12)
              | (enc_e2m1(d.x * f) << 16) | (enc_e2m1(d.y * f) << 20)
              | (enc_e2m1(d.z * f) << 24) | (enc_e2m1(d.w * f) << 28);
  *reinterpret_cast<unsigned*>(Wn4 + (size_t)outr * 256 + l * 4) = pk;

  const unsigned bv = (unsigned)(127 + sg) & 0xffu;
  const int base = l & 48;
  const unsigned bA = __shfl(bv, base + 0, 64);
  const unsigned bB = __shfl(bv, base + 4, 64);
  const unsigned bC = __shfl(bv, base + 8, 64);
  const unsigned bD = __shfl(bv, base + 12, 64);
  if ((l & 15) == 0)
    sigw[(size_t)outr * 4 + (l >> 4)] = bA | (bB << 8) | (bC << 16) | (bD << 24);
}

// K-prep: normalize embeddings -> fp8 En8 AND exact f32 target-class margin terms
__global__ __launch_bounds__(64) void k_prep(const float* __restrict__ E,
                                             const int* __restrict__ lab,
                                             const float* __restrict__ W,
                                             unsigned char* __restrict__ En8,
                                             float* __restrict__ delta,
                                             float* __restrict__ tl) {
  const int b = blockIdx.x, l = threadIdx.x;
  const float4* pe = reinterpret_cast<const float4*>(E + (size_t)b * DIM + l * 8);
  float4 e0 = pe[0], e1 = pe[1];
  float es = e0.x*e0.x + e0.y*e0.y + e0.z*e0.z + e0.w*e0.w
           + e1.x*e1.x + e1.y*e1.y + e1.z*e1.z + e1.w*e1.w;
  es = wave_sum(es);
  const float inv = rsqrtf(es);
  uint2 o;
  o.x = pack4_fp8(e0.x*inv, e0.y*inv, e0.z*inv, e0.w*inv);
  o.y = pack4_fp8(e1.x*inv, e1.y*inv, e1.z*inv, e1.w*inv);
  *reinterpret_cast<uint2*>(En8 + (size_t)b * DIM + l * 8) = o;

  const int L = lab[b];
  float mx = -2.f;
#pragma unroll
  for (int k = 0; k < KSUB; ++k) {
    const float4* pw = reinterpret_cast<const float4*>(W + (size_t)(L * KSUB + k) * DIM + l * 8);
    float4 w0 = pw[0], w1 = pw[1];
    float ds = e0.x*w0.x + e0.y*w0.y + e0.z*w0.z + e0.w*w0.w
             + e1.x*w1.x + e1.y*w1.y + e1.z*w1.z + e1.w*w1.w;
    float ws = w0.x*w0.x + w0.y*w0.y + w0.z*w0.z + w0.w*w0.w
             + w1.x*w1.x + w1.y*w1.y + w1.z*w1.z + w1.w*w1.w;
    ds = wave_sum(ds);
    ws = wave_sum(ws);
    float ck = ds * rsqrtf(es * ws);
    mx = fmaxf(mx, ck);
  }
  if (l == 0) {
    float cc = fminf(fmaxf(mx, -1.f + EPSC), 1.f - EPSC);
    float sn = sqrtf(fmaxf(1.f - cc * cc, 0.f));
    float mg = cc * COSM - sn * SINM;           // cos(arccos(cc)+m)
    delta[b] = __expf(SCALEF * mg) - __expf(SCALEF * cc);
    tl[b]    = SCALEF * mg;
  }
}

// stage one 48-row fp4 tile (12 KB) AND its 768 B scale block via global_load_lds.
// Tile: LDS slot s of row r holds global chunk s ^ (r&15) (involution).
// Scales: linear at lbuf+12288 (row r's uint4 at +r*16), staged by wave 4.
__device__ __forceinline__ void stage4(const unsigned char* __restrict__ Wt,
                                       const unsigned char* __restrict__ sgt,
                                       unsigned char* lbuf, int wv, int lane) {
  {
    const int r = wv * 4 + (lane >> 4);
    const int m = (lane & 15) ^ (r & 15);
    __builtin_amdgcn_global_load_lds(
        (const __attribute__((address_space(1))) unsigned int*)(Wt + (size_t)r * 256 + m * 16),
        (__attribute__((address_space(3))) unsigned int*)(lbuf + wv * 1024),
        16, 0, 0);
  }
  if (wv < 4) {
    const int r = 32 + wv * 4 + (lane >> 4);
    const int m = (lane & 15) ^ (r & 15);
    __builtin_amdgcn_global_load_lds(
        (const __attribute__((address_space(1))) unsigned int*)(Wt + (size_t)r * 256 + m * 16),
        (__attribute__((address_space(3))) unsigned int*)(lbuf + (8 + wv) * 1024),
        16, 0, 0);
  } else if (wv == 4 && lane < 48) {
    __builtin_amdgcn_global_load_lds(
        (const __attribute__((address_space(1))) unsigned int*)(sgt + lane * 16),
        (__attribute__((address_space(3))) unsigned int*)(lbuf + TILE4B),
        16, 0, 0);
  }
}

// K1: mixed MX MFMA — A = W fp4 (cbsz=4, per-block scales from LDS), B = E fp8.
// Permuted rows: acc[t][j][reg] = sub-center t of class 4g+reg -> sub-center
// max is pure in-lane VALU (no shuffles, no branches).
__global__ __launch_bounds__(512, 4) void k_main(const unsigned char* __restrict__ Wn4,
                                                 const unsigned char* __restrict__ sigw,
                                                 const unsigned char* __restrict__ En8,
                                                 float* __restrict__ Zp) {
  __shared__ __align__(16) unsigned char wlds[2 * TILESB];   // 26 KB
  const int tid  = threadIdx.x;
  const int lane = tid & 63;
  const int wv   = tid >> 6;
  const int g    = lane >> 4;
  const int c    = lane & 15;
  const int rg   = blockIdx.x & (NRG - 1);   // partners share XCD: blk%8 = rg%8
  const int cg   = blockIdx.x >> 7;

  // ---- load this wave's E fragments once: 2 x 4 x i32x8 = 64 VGPRs ----
  i32x8 bfr[NJ][NKQ];
#pragma unroll
  for (int j = 0; j < NJ; ++j) {
    const int col = cg * 256 + wv * 32 + j * 16 + c;
#pragma unroll
    for (int kq = 0; kq < NKQ; ++kq)
      bfr[j][kq] = *reinterpret_cast<const i32x8*>(
          En8 + (size_t)col * DIM + kq * 128 + g * 32);
  }

  float zreg[NJ];
#pragma unroll
  for (int j = 0; j < NJ; ++j) zreg[j] = 0.f;

  stage4(Wn4 + (size_t)rg * TILE4B, sigw + (size_t)rg * 768, wlds, wv, lane);
  __syncthreads();
  int cur = 0;

  for (int tile = rg; tile < NTILES; tile += NRG) {
    const int nxt = tile + NRG;
    if (nxt < NTILES)
      stage4(Wn4 + (size_t)nxt * TILE4B, sigw + (size_t)nxt * 768,
             wlds + (cur ^ 1) * TILESB, wv, lane);

    const unsigned char* lbuf = wlds + cur * TILESB;

    // per-t scale words for this lane's rows (r = t*16+c): 3 x ds_read_b128
    uint4 sgv[TW];
#pragma unroll
    for (int t = 0; t < TW; ++t)
      sgv[t] = *reinterpret_cast<const uint4*>(lbuf + TILE4B + (t * 16 + c) * 16);

    f32x4 acc[TW][NJ];
#pragma unroll
    for (int t = 0; t < TW; ++t)
#pragma unroll
      for (int j = 0; j < NJ; ++j) acc[t][j] = (f32x4){0.f, 0.f, 0.f, 0.f};

#pragma unroll
    for (int kq = 0; kq < NKQ; ++kq) {
#pragma unroll
      for (int t = 0; t < TW; ++t) {
        const int r = t * 16 + c;                 // r & 15 == c
        const unsigned swd = (&sgv[t].x)[kq];     // static after unroll
        const unsigned sA = ((swd >> (g * 8)) & 0xffu) * 0x01010101u;
        const int s = (kq * 4 + g) ^ c;
        const int4 v = *reinterpret_cast<const int4*>(lbuf + r * 256 + s * 16);
        i32x8 av = (i32x8){0, 0, 0, 0, 0, 0, 0, 0};
        av[0] = v.x; av[1] = v.y; av[2] = v.z; av[3] = v.w;
#pragma unroll
        for (int j = 0; j < NJ; ++j)
          acc[t][j] = __builtin_amdgcn_mfma_scale_f32_16x16x128_f8f6f4(
              av, bfr[j][kq], acc[t][j], 4, 0, 0, (int)sA, 0, SCL1);
      }
    }

    // ---- epilogue: sub-center max is IN-LANE (permuted rows): max3 + exp ----
#pragma unroll
    for (int j = 0; j < NJ; ++j) {
      float zc = 0.f;
#pragma unroll
      for (int q = 0; q < 4; ++q) {
        const float mx3 = fmaxf(fmaxf(acc[0][j][q], acc[1][j][q]), acc[2][j][q]);
        zc += eterm(mx3);
      }
      zreg[j] += zc;                 // cross-lane reduce ONCE at end
    }

    __syncthreads();   // staging drained + all waves done with cur
    cur ^= 1;
  }

  // ---- final cross-lane reduction ----
#pragma unroll
  for (int j = 0; j < NJ; ++j) {
    zreg[j] += __shfl_xor(zreg[j], 16, 64);
    zreg[j] += __shfl_xor(zreg[j], 32, 64);
  }
  if (g == 0) {
#pragma unroll
    for (int j = 0; j < NJ; ++j)
      Zp[(size_t)rg * BQ + cg * 256 + wv * 32 + j * 16 + c] = zreg[j];
  }
}

// K3: Z[b] = sum over 128 row-group partials; per-row loss; block partial sums
__global__ __launch_bounds__(256) void k_reduce(const float* __restrict__ Zp,
                                                const float* __restrict__ delta,
                                                const float* __restrict__ tl,
                                                float* __restrict__ part) {
  const int b = blockIdx.x * 256 + threadIdx.x;
  float z = 0.f;
#pragma unroll 8
  for (int nb = 0; nb < NRG; ++nb) z += Zp[(size_t)nb * BQ + b];
  float lossb = logf(z + delta[b]) - tl[b];
  __shared__ float sm[256];
  sm[threadIdx.x] = lossb;
  __syncthreads();
#pragma unroll
  for (int s = 128; s > 0; s >>= 1) {
    if (threadIdx.x < s) sm[threadIdx.x] += sm[threadIdx.x + s];
    __syncthreads();
  }
  if (threadIdx.x == 0) part[blockIdx.x] = sm[0];
}

__global__ void k_final(const float* __restrict__ part, float* __restrict__ out) {
  out[0] = (part[0] + part[1] + part[2] + part[3]) * (1.0f / BQ);
}

extern "C" void kernel_launch(void* const* d_in, const int* in_sizes, int n_in,
                              void* d_out, int out_size, void* d_ws, size_t ws_size,
                              hipStream_t stream) {
  const float* E  = (const float*)d_in[0];
  const int* lab  = (const int*)d_in[1];
  const float* W  = (const float*)d_in[2];

  char* ws = (char*)d_ws;
  unsigned char* En8 = (unsigned char*)ws;                            // 512 KB
  unsigned char* Wn4 = (unsigned char*)(ws + (size_t)BQ * DIM);       // 38.4 MB
  unsigned* sigw = (unsigned*)(ws + (size_t)BQ * DIM + (size_t)NROWSW * 256);  // 2.4 MB
  char* after = (char*)(sigw + (size_t)NROWSW * 4);
  float* Zp    = (float*)after;                                       // 512 KB
  float* delta = Zp + (size_t)NRG * BQ;
  float* tl    = delta + BQ;
  float* part  = tl + BQ;

  hipLaunchKernelGGL(k_prenorm, dim3(NROWSW / 4), dim3(256), 0, stream, W, Wn4, sigw);
  hipLaunchKernelGGL(k_prep,    dim3(BQ),         dim3(64),  0, stream, E, lab, W, En8, delta, tl);
  hipLaunchKernelGGL(k_main,    dim3(NRG * NCG),  dim3(512), 0, stream, Wn4, (unsigned char*)sigw, En8, Zp);
  hipLaunchKernelGGL(k_reduce,  dim3(4),          dim3(256), 0, stream, Zp, delta, tl, part);
  hipLaunchKernelGGL(k_final,   dim3(1),          dim3(1),   0, stream, part, (float*)d_out);
}

// Round 15
// 138.460 us; speedup vs baseline: 1.6525x; 1.0161x over previous
//
#include <hip/hip_runtime.h>
#include <math.h>

typedef __attribute__((ext_vector_type(4))) float f32x4;
typedef __attribute__((ext_vector_type(8))) int  i32x8;

#define NCLS   50000
#define KSUB   3
#define DIM    512            // elements; fp4 row = 256 B, fp8 row = 512 B
#define NROWSW (NCLS*KSUB)    // 150000
#define BQ     1024

#define SCALEF 30.0f
#define EPSC   1e-7f
#define COSM   0.8775825618903728f
#define SINM   0.4794255386042030f

#define BN     48             // weight rows per tile (lcm(16,3))
#define TW     3              // 16-row MFMA tiles = 3 sub-centers after permutation
#define NJ     2              // 16-col B subtiles per wave (32 cols/wave, 256/block)
#define NKQ    4              // K=512 / 128 per scaled MFMA
#define NTILES (NROWSW/BN)    // 3125
#define NRG    128            // row groups
#define NCG    4              // col groups of 256; partners (same rg) share an XCD
#define TILE4B (BN*256)       // 12288 B tile data (fp4)
#define TILESB (TILE4B+1024)  // + 768 B scales (padded to 1 KB) per LDS buffer
#define SCL1   0x7F7F7F7F     // E8M0 scale = 1.0 in every byte

__device__ __forceinline__ float wave_sum(float v) {
#pragma unroll
  for (int m = 1; m < 64; m <<= 1) v += __shfl_xor(v, m, 64);
  return v;
}

__device__ __forceinline__ unsigned pack4_fp8(float a, float b, float c, float d) {
  int v = 0;
  v = __builtin_amdgcn_cvt_pk_fp8_f32(a, b, v, false);
  v = __builtin_amdgcn_cvt_pk_fp8_f32(c, d, v, true);
  return (unsigned)v;
}

__device__ __forceinline__ float eterm(float v) {
  v = fminf(fmaxf(v, -1.f + EPSC), 1.f - EPSC);
  return __expf(SCALEF * v);
}

// nearest e2m1 nibble: values {0,.5,1,1.5,2,3,4,6}; patterns 0..7 in that order
__device__ __forceinline__ unsigned enc_e2m1(float x) {
  unsigned s = (__float_as_uint(x) >> 31) << 3;
  float v = fabsf(x);
  unsigned m;
  if      (v < 0.25f) m = 0;
  else if (v < 0.75f) m = 1;
  else if (v < 1.25f) m = 2;
  else if (v < 1.75f) m = 3;
  else if (v < 2.5f)  m = 4;
  else if (v < 3.5f)  m = 5;
  else if (v < 5.0f)  m = 6;
  else                m = 7;
  return s | m;
}

// K-pre: normalize rows AND MX-fp4 quantize (validated R12/R13), rows PERMUTED
// within each 48-row tile: orig 3q+k (class q, sub-center k) -> q + 16k.
__global__ __launch_bounds__(256) void k_prenorm(const float* __restrict__ W,
                                                 unsigned char* __restrict__ Wn4,
                                                 unsigned* __restrict__ sigw) {
  const int row = blockIdx.x * 4 + (threadIdx.x >> 6);
  const int l = threadIdx.x & 63;
  const int tile = row / BN;
  const int rr   = row - tile * BN;
  const int outr = tile * BN + rr / 3 + 16 * (rr % 3);   // permuted destination row

  const float4* p = reinterpret_cast<const float4*>(W + (size_t)row * DIM + l * 8);
  float4 a = p[0], d = p[1];
  float ss = a.x*a.x + a.y*a.y + a.z*a.z + a.w*a.w
           + d.x*d.x + d.y*d.y + d.z*d.z + d.w*d.w;
  ss = wave_sum(ss);
  const float inv = rsqrtf(ss);

  float am = fmaxf(fmaxf(fmaxf(fabsf(a.x), fabsf(a.y)), fmaxf(fabsf(a.z), fabsf(a.w))),
                   fmaxf(fmaxf(fabsf(d.x), fabsf(d.y)), fmaxf(fabsf(d.z), fabsf(d.w)))) * inv;
  am = fmaxf(am, __shfl_xor(am, 1, 64));     // 32-elem block = 4 lanes
  am = fmaxf(am, __shfl_xor(am, 2, 64));

  const float t6 = am * (1.0f / 6.0f);
  const unsigned ut = __float_as_uint(t6);
  int sg = (int)((ut >> 23) & 255) - 127 + ((ut & 0x7fffffu) ? 1 : 0);
  if (!(am > 0.f)) sg = -100;
  sg = sg < -100 ? -100 : (sg > 100 ? 100 : sg);
  const float f = inv * __uint_as_float((unsigned)(127 - sg) << 23);  // inv * 2^-sg

  unsigned pk =  enc_e2m1(a.x * f)        | (enc_e2m1(a.y * f) << 4)
              | (enc_e2m1(a.z * f) << 8)  | (enc_e2m1(a.w * f) << 12)
              | (enc_e2m1(d.x * f) << 16) | (enc_e2m1(d.y * f) << 20)
              | (enc_e2m1(d.z * f) << 24) | (enc_e2m1(d.w * f) << 28);
  *reinterpret_cast<unsigned*>(Wn4 + (size_t)outr * 256 + l * 4) = pk;

  const unsigned bv = (unsigned)(127 + sg) & 0xffu;
  const int base = l & 48;
  const unsigned bA = __shfl(bv, base + 0, 64);
  const unsigned bB = __shfl(bv, base + 4, 64);
  const unsigned bC = __shfl(bv, base + 8, 64);
  const unsigned bD = __shfl(bv, base + 12, 64);
  if ((l & 15) == 0)
    sigw[(size_t)outr * 4 + (l >> 4)] = bA | (bB << 8) | (bC << 16) | (bD << 24);
}

// K-prep: normalize embeddings -> fp8 En8 AND exact f32 target-class margin terms
__global__ __launch_bounds__(64) void k_prep(const float* __restrict__ E,
                                             const int* __restrict__ lab,
                                             const float* __restrict__ W,
                                             unsigned char* __restrict__ En8,
                                             float* __restrict__ delta,
                                             float* __restrict__ tl) {
  const int b = blockIdx.x, l = threadIdx.x;
  const float4* pe = reinterpret_cast<const float4*>(E + (size_t)b * DIM + l * 8);
  float4 e0 = pe[0], e1 = pe[1];
  float es = e0.x*e0.x + e0.y*e0.y + e0.z*e0.z + e0.w*e0.w
           + e1.x*e1.x + e1.y*e1.y + e1.z*e1.z + e1.w*e1.w;
  es = wave_sum(es);
  const float inv = rsqrtf(es);
  uint2 o;
  o.x = pack4_fp8(e0.x*inv, e0.y*inv, e0.z*inv, e0.w*inv);
  o.y = pack4_fp8(e1.x*inv, e1.y*inv, e1.z*inv, e1.w*inv);
  *reinterpret_cast<uint2*>(En8 + (size_t)b * DIM + l * 8) = o;

  const int L = lab[b];
  float mx = -2.f;
#pragma unroll
  for (int k = 0; k < KSUB; ++k) {
    const float4* pw = reinterpret_cast<const float4*>(W + (size_t)(L * KSUB + k) * DIM + l * 8);
    float4 w0 = pw[0], w1 = pw[1];
    float ds = e0.x*w0.x + e0.y*w0.y + e0.z*w0.z + e0.w*w0.w
             + e1.x*w1.x + e1.y*w1.y + e1.z*w1.z + e1.w*w1.w;
    float ws = w0.x*w0.x + w0.y*w0.y + w0.z*w0.z + w0.w*w0.w
             + w1.x*w1.x + w1.y*w1.y + w1.z*w1.z + w1.w*w1.w;
    ds = wave_sum(ds);
    ws = wave_sum(ws);
    float ck = ds * rsqrtf(es * ws);
    mx = fmaxf(mx, ck);
  }
  if (l == 0) {
    float cc = fminf(fmaxf(mx, -1.f + EPSC), 1.f - EPSC);
    float sn = sqrtf(fmaxf(1.f - cc * cc, 0.f));
    float mg = cc * COSM - sn * SINM;           // cos(arccos(cc)+m)
    delta[b] = __expf(SCALEF * mg) - __expf(SCALEF * cc);
    tl[b]    = SCALEF * mg;
  }
}

// stage one 48-row fp4 tile (12 KB) AND its 768 B scale block via global_load_lds.
// Tile: LDS slot s of row r holds global chunk s ^ (r&15) (involution).
// Scales: linear at lbuf+12288 (row r's uint4 at +r*16), staged by wave 4.
__device__ __forceinline__ void stage4(const unsigned char* __restrict__ Wt,
                                       const unsigned char* __restrict__ sgt,
                                       unsigned char* lbuf, int wv, int lane) {
  {
    const int r = wv * 4 + (lane >> 4);
    const int m = (lane & 15) ^ (r & 15);
    __builtin_amdgcn_global_load_lds(
        (const __attribute__((address_space(1))) unsigned int*)(Wt + (size_t)r * 256 + m * 16),
        (__attribute__((address_space(3))) unsigned int*)(lbuf + wv * 1024),
        16, 0, 0);
  }
  if (wv < 4) {
    const int r = 32 + wv * 4 + (lane >> 4);
    const int m = (lane & 15) ^ (r & 15);
    __builtin_amdgcn_global_load_lds(
        (const __attribute__((address_space(1))) unsigned int*)(Wt + (size_t)r * 256 + m * 16),
        (__attribute__((address_space(3))) unsigned int*)(lbuf + (8 + wv) * 1024),
        16, 0, 0);
  } else if (wv == 4 && lane < 48) {
    __builtin_amdgcn_global_load_lds(
        (const __attribute__((address_space(1))) unsigned int*)(sgt + lane * 16),
        (__attribute__((address_space(3))) unsigned int*)(lbuf + TILE4B),
        16, 0, 0);
  }
}

// K1: mixed MX MFMA — A = W fp4 (cbsz=4, per-block scales from LDS), B = E fp8.
// R15: 4 LDS buffers, TWO tiles per barrier round (halved lockstep frequency).
// Per-tile compute byte-identical to verified R14.
__global__ __launch_bounds__(512, 4) void k_main(const unsigned char* __restrict__ Wn4,
                                                 const unsigned char* __restrict__ sigw,
                                                 const unsigned char* __restrict__ En8,
                                                 float* __restrict__ Zp) {
  __shared__ __align__(16) unsigned char wlds[4 * TILESB];   // 52 KB -> 2 blocks/CU
  const int tid  = threadIdx.x;
  const int lane = tid & 63;
  const int wv   = tid >> 6;
  const int g    = lane >> 4;
  const int c    = lane & 15;
  const int rg   = blockIdx.x & (NRG - 1);   // partners share XCD: blk%8 = rg%8
  const int cg   = blockIdx.x >> 7;

  // ---- load this wave's E fragments once: 2 x 4 x i32x8 = 64 VGPRs ----
  i32x8 bfr[NJ][NKQ];
#pragma unroll
  for (int j = 0; j < NJ; ++j) {
    const int col = cg * 256 + wv * 32 + j * 16 + c;
#pragma unroll
    for (int kq = 0; kq < NKQ; ++kq)
      bfr[j][kq] = *reinterpret_cast<const i32x8*>(
          En8 + (size_t)col * DIM + kq * 128 + g * 32);
  }

  float zreg[NJ];
#pragma unroll
  for (int j = 0; j < NJ; ++j) zreg[j] = 0.f;

  // per-tile compute (verified R14 body), accumulates into zreg
  auto compute_tile = [&](const unsigned char* lbuf) {
    uint4 sgv[TW];
#pragma unroll
    for (int t = 0; t < TW; ++t)
      sgv[t] = *reinterpret_cast<const uint4*>(lbuf + TILE4B + (t * 16 + c) * 16);

    f32x4 acc[TW][NJ];
#pragma unroll
    for (int t = 0; t < TW; ++t)
#pragma unroll
      for (int j = 0; j < NJ; ++j) acc[t][j] = (f32x4){0.f, 0.f, 0.f, 0.f};

#pragma unroll
    for (int kq = 0; kq < NKQ; ++kq) {
#pragma unroll
      for (int t = 0; t < TW; ++t) {
        const int r = t * 16 + c;                 // r & 15 == c
        const unsigned swd = (&sgv[t].x)[kq];     // static after unroll
        const unsigned sA = ((swd >> (g * 8)) & 0xffu) * 0x01010101u;
        const int s = (kq * 4 + g) ^ c;
        const int4 v = *reinterpret_cast<const int4*>(lbuf + r * 256 + s * 16);
        i32x8 av = (i32x8){0, 0, 0, 0, 0, 0, 0, 0};
        av[0] = v.x; av[1] = v.y; av[2] = v.z; av[3] = v.w;
#pragma unroll
        for (int j = 0; j < NJ; ++j)
          acc[t][j] = __builtin_amdgcn_mfma_scale_f32_16x16x128_f8f6f4(
              av, bfr[j][kq], acc[t][j], 4, 0, 0, (int)sA, 0, SCL1);
      }
    }

    // epilogue: sub-center max IN-LANE (permuted rows): max3 + exp
#pragma unroll
    for (int j = 0; j < NJ; ++j) {
      float zc = 0.f;
#pragma unroll
      for (int q = 0; q < 4; ++q) {
        const float mx3 = fmaxf(fmaxf(acc[0][j][q], acc[1][j][q]), acc[2][j][q]);
        zc += eterm(mx3);
      }
      zreg[j] += zc;
    }
  };

  // ---- 4-buffer, 2-tiles-per-barrier pipeline ----
  unsigned char* B0 = wlds;
  unsigned char* B1 = wlds + TILESB;
  unsigned char* B2 = wlds + 2 * TILESB;
  unsigned char* B3 = wlds + 3 * TILESB;

  stage4(Wn4 + (size_t)rg * TILE4B, sigw + (size_t)rg * 768, B0, wv, lane);
  stage4(Wn4 + (size_t)(rg + NRG) * TILE4B, sigw + (size_t)(rg + NRG) * 768, B1, wv, lane);
  __syncthreads();

  for (int t = rg; t < NTILES; t += 2 * NRG) {
    const int t1 = t + NRG, t2 = t + 2 * NRG, t3 = t + 3 * NRG;
    if (t2 < NTILES)
      stage4(Wn4 + (size_t)t2 * TILE4B, sigw + (size_t)t2 * 768, B2, wv, lane);
    if (t3 < NTILES)
      stage4(Wn4 + (size_t)t3 * TILE4B, sigw + (size_t)t3 * 768, B3, wv, lane);

    compute_tile(B0);
    if (t1 < NTILES) compute_tile(B1);

    __syncthreads();   // readers done with B0/B1 + B2/B3 stages drained
    unsigned char* x;
    x = B0; B0 = B2; B2 = x;
    x = B1; B1 = B3; B3 = x;
  }

  // ---- final cross-lane reduction ----
#pragma unroll
  for (int j = 0; j < NJ; ++j) {
    zreg[j] += __shfl_xor(zreg[j], 16, 64);
    zreg[j] += __shfl_xor(zreg[j], 32, 64);
  }
  if (g == 0) {
#pragma unroll
    for (int j = 0; j < NJ; ++j)
      Zp[(size_t)rg * BQ + cg * 256 + wv * 32 + j * 16 + c] = zreg[j];
  }
}

// K3: Z[b] = sum over 128 row-group partials; per-row loss; block partial sums
__global__ __launch_bounds__(256) void k_reduce(const float* __restrict__ Zp,
                                                const float* __restrict__ delta,
                                                const float* __restrict__ tl,
                                                float* __restrict__ part) {
  const int b = blockIdx.x * 256 + threadIdx.x;
  float z = 0.f;
#pragma unroll 8
  for (int nb = 0; nb < NRG; ++nb) z += Zp[(size_t)nb * BQ + b];
  float lossb = logf(z + delta[b]) - tl[b];
  __shared__ float sm[256];
  sm[threadIdx.x] = lossb;
  __syncthreads();
#pragma unroll
  for (int s = 128; s > 0; s >>= 1) {
    if (threadIdx.x < s) sm[threadIdx.x] += sm[threadIdx.x + s];
    __syncthreads();
  }
  if (threadIdx.x == 0) part[blockIdx.x] = sm[0];
}

__global__ void k_final(const float* __restrict__ part, float* __restrict__ out) {
  out[0] = (part[0] + part[1] + part[2] + part[3]) * (1.0f / BQ);
}

extern "C" void kernel_launch(void* const* d_in, const int* in_sizes, int n_in,
                              void* d_out, int out_size, void* d_ws, size_t ws_size,
                              hipStream_t stream) {
  const float* E  = (const float*)d_in[0];
  const int* lab  = (const int*)d_in[1];
  const float* W  = (const float*)d_in[2];

  char* ws = (char*)d_ws;
  unsigned char* En8 = (unsigned char*)ws;                            // 512 KB
  unsigned char* Wn4 = (unsigned char*)(ws + (size_t)BQ * DIM);       // 38.4 MB
  unsigned* sigw = (unsigned*)(ws + (size_t)BQ * DIM + (size_t)NROWSW * 256);  // 2.4 MB
  char* after = (char*)(sigw + (size_t)NROWSW * 4);
  float* Zp    = (float*)after;                                       // 512 KB
  float* delta = Zp + (size_t)NRG * BQ;
  float* tl    = delta + BQ;
  float* part  = tl + BQ;

  hipLaunchKernelGGL(k_prenorm, dim3(NROWSW / 4), dim3(256), 0, stream, W, Wn4, sigw);
  hipLaunchKernelGGL(k_prep,    dim3(BQ),         dim3(64),  0, stream, E, lab, W, En8, delta, tl);
  hipLaunchKernelGGL(k_main,    dim3(NRG * NCG),  dim3(512), 0, stream, Wn4, (unsigned char*)sigw, En8, Zp);
  hipLaunchKernelGGL(k_reduce,  dim3(4),          dim3(256), 0, stream, Zp, delta, tl, part);
  hipLaunchKernelGGL(k_final,   dim3(1),          dim3(1),   0, stream, part, (float*)d_out);
}

// Round 16
// 137.990 us; speedup vs baseline: 1.6581x; 1.0034x over previous
//
#include <hip/hip_runtime.h>
#include <math.h>

typedef __attribute__((ext_vector_type(4))) float f32x4;
typedef __attribute__((ext_vector_type(8))) int  i32x8;

#define NCLS   50000
#define KSUB   3
#define DIM    512            // elements; fp4 row = 256 B, fp8 row = 512 B
#define NROWSW (NCLS*KSUB)    // 150000
#define BQ     1024

#define SCALEF 30.0f
#define EPSC   1e-7f
#define COSM   0.8775825618903728f
#define SINM   0.4794255386042030f

#define BN     48             // weight rows per tile (lcm(16,3))
#define TW     3              // 16-row MFMA tiles = 3 sub-centers after permutation
#define NJ     2              // 16-col B subtiles per wave (32 cols/wave, 256/block)
#define NKQ    4              // K=512 / 128 per scaled MFMA
#define NTILES (NROWSW/BN)    // 3125
#define NRG    128            // row groups
#define NCG    4              // col groups of 256; partners (same rg) share an XCD
#define TILE4B (BN*256)       // 12288 B tile data (fp4)
#define TILESB (TILE4B+1024)  // + 768 B scales (padded to 1 KB) per LDS buffer
#define SCL1   0x7F7F7F7F     // E8M0 scale = 1.0 in every byte

__device__ __forceinline__ float wave_sum(float v) {
#pragma unroll
  for (int m = 1; m < 64; m <<= 1) v += __shfl_xor(v, m, 64);
  return v;
}

__device__ __forceinline__ unsigned pack4_fp8(float a, float b, float c, float d) {
  int v = 0;
  v = __builtin_amdgcn_cvt_pk_fp8_f32(a, b, v, false);
  v = __builtin_amdgcn_cvt_pk_fp8_f32(c, d, v, true);
  return (unsigned)v;
}

__device__ __forceinline__ float eterm(float v) {
  v = fminf(fmaxf(v, -1.f + EPSC), 1.f - EPSC);
  return __expf(SCALEF * v);
}

// nearest e2m1 nibble: values {0,.5,1,1.5,2,3,4,6}; patterns 0..7 in that order
__device__ __forceinline__ unsigned enc_e2m1(float x) {
  unsigned s = (__float_as_uint(x) >> 31) << 3;
  float v = fabsf(x);
  unsigned m;
  if      (v < 0.25f) m = 0;
  else if (v < 0.75f) m = 1;
  else if (v < 1.25f) m = 2;
  else if (v < 1.75f) m = 3;
  else if (v < 2.5f)  m = 4;
  else if (v < 3.5f)  m = 5;
  else if (v < 5.0f)  m = 6;
  else                m = 7;
  return s | m;
}

// K-pre: normalize rows AND MX-fp4 quantize (validated R12/R13), rows PERMUTED
// within each 48-row tile: orig 3q+k (class q, sub-center k) -> q + 16k.
__global__ __launch_bounds__(256) void k_prenorm(const float* __restrict__ W,
                                                 unsigned char* __restrict__ Wn4,
                                                 unsigned* __restrict__ sigw) {
  const int row = blockIdx.x * 4 + (threadIdx.x >> 6);
  const int l = threadIdx.x & 63;
  const int tile = row / BN;
  const int rr   = row - tile * BN;
  const int outr = tile * BN + rr / 3 + 16 * (rr % 3);   // permuted destination row

  const float4* p = reinterpret_cast<const float4*>(W + (size_t)row * DIM + l * 8);
  float4 a = p[0], d = p[1];
  float ss = a.x*a.x + a.y*a.y + a.z*a.z + a.w*a.w
           + d.x*d.x + d.y*d.y + d.z*d.z + d.w*d.w;
  ss = wave_sum(ss);
  const float inv = rsqrtf(ss);

  float am = fmaxf(fmaxf(fmaxf(fabsf(a.x), fabsf(a.y)), fmaxf(fabsf(a.z), fabsf(a.w))),
                   fmaxf(fmaxf(fabsf(d.x), fabsf(d.y)), fmaxf(fabsf(d.z), fabsf(d.w)))) * inv;
  am = fmaxf(am, __shfl_xor(am, 1, 64));     // 32-elem block = 4 lanes
  am = fmaxf(am, __shfl_xor(am, 2, 64));

  const float t6 = am * (1.0f / 6.0f);
  const unsigned ut = __float_as_uint(t6);
  int sg = (int)((ut >> 23) & 255) - 127 + ((ut & 0x7fffffu) ? 1 : 0);
  if (!(am > 0.f)) sg = -100;
  sg = sg < -100 ? -100 : (sg > 100 ? 100 : sg);
  const float f = inv * __uint_as_float((unsigned)(127 - sg) << 23);  // inv * 2^-sg

  unsigned pk =  enc_e2m1(a.x * f)        | (enc_e2m1(a.y * f) << 4)
              | (enc_e2m1(a.z * f) << 8)  | (enc_e2m1(a.w * f) << 12)
              | (enc_e2m1(d.x * f) << 16) | (enc_e2m1(d.y * f) << 20)
              | (enc_e2m1(d.z * f) << 24) | (enc_e2m1(d.w * f) << 28);
  *reinterpret_cast<unsigned*>(Wn4 + (size_t)outr * 256 + l * 4) = pk;

  const unsigned bv = (unsigned)(127 + sg) & 0xffu;
  const int base = l & 48;
  const unsigned bA = __shfl(bv, base + 0, 64);
  const unsigned bB = __shfl(bv, base + 4, 64);
  const unsigned bC = __shfl(bv, base + 8, 64);
  const unsigned bD = __shfl(bv, base + 12, 64);
  if ((l & 15) == 0)
    sigw[(size_t)outr * 4 + (l >> 4)] = bA | (bB << 8) | (bC << 16) | (bD << 24);
}

// K-prep: normalize embeddings -> fp8 En8 AND exact f32 target-class margin terms
__global__ __launch_bounds__(64) void k_prep(const float* __restrict__ E,
                                             const int* __restrict__ lab,
                                             const float* __restrict__ W,
                                             unsigned char* __restrict__ En8,
                                             float* __restrict__ delta,
                                             float* __restrict__ tl) {
  const int b = blockIdx.x, l = threadIdx.x;
  const float4* pe = reinterpret_cast<const float4*>(E + (size_t)b * DIM + l * 8);
  float4 e0 = pe[0], e1 = pe[1];
  float es = e0.x*e0.x + e0.y*e0.y + e0.z*e0.z + e0.w*e0.w
           + e1.x*e1.x + e1.y*e1.y + e1.z*e1.z + e1.w*e1.w;
  es = wave_sum(es);
  const float inv = rsqrtf(es);
  uint2 o;
  o.x = pack4_fp8(e0.x*inv, e0.y*inv, e0.z*inv, e0.w*inv);
  o.y = pack4_fp8(e1.x*inv, e1.y*inv, e1.z*inv, e1.w*inv);
  *reinterpret_cast<uint2*>(En8 + (size_t)b * DIM + l * 8) = o;

  const int L = lab[b];
  float mx = -2.f;
#pragma unroll
  for (int k = 0; k < KSUB; ++k) {
    const float4* pw = reinterpret_cast<const float4*>(W + (size_t)(L * KSUB + k) * DIM + l * 8);
    float4 w0 = pw[0], w1 = pw[1];
    float ds = e0.x*w0.x + e0.y*w0.y + e0.z*w0.z + e0.w*w0.w
             + e1.x*w1.x + e1.y*w1.y + e1.z*w1.z + e1.w*w1.w;
    float ws = w0.x*w0.x + w0.y*w0.y + w0.z*w0.z + w0.w*w0.w
             + w1.x*w1.x + w1.y*w1.y + w1.z*w1.z + w1.w*w1.w;
    ds = wave_sum(ds);
    ws = wave_sum(ws);
    float ck = ds * rsqrtf(es * ws);
    mx = fmaxf(mx, ck);
  }
  if (l == 0) {
    float cc = fminf(fmaxf(mx, -1.f + EPSC), 1.f - EPSC);
    float sn = sqrtf(fmaxf(1.f - cc * cc, 0.f));
    float mg = cc * COSM - sn * SINM;           // cos(arccos(cc)+m)
    delta[b] = __expf(SCALEF * mg) - __expf(SCALEF * cc);
    tl[b]    = SCALEF * mg;
  }
}

// stage one 48-row fp4 tile (12 KB) AND its 768 B scale block via global_load_lds.
// Tile: LDS slot s of row r holds global chunk s ^ (r&15) (involution).
// Scales: linear at lbuf+12288 (row r's uint4 at +r*16), staged by wave 4.
__device__ __forceinline__ void stage4(const unsigned char* __restrict__ Wt,
                                       const unsigned char* __restrict__ sgt,
                                       unsigned char* lbuf, int wv, int lane) {
  {
    const int r = wv * 4 + (lane >> 4);
    const int m = (lane & 15) ^ (r & 15);
    __builtin_amdgcn_global_load_lds(
        (const __attribute__((address_space(1))) unsigned int*)(Wt + (size_t)r * 256 + m * 16),
        (__attribute__((address_space(3))) unsigned int*)(lbuf + wv * 1024),
        16, 0, 0);
  }
  if (wv < 4) {
    const int r = 32 + wv * 4 + (lane >> 4);
    const int m = (lane & 15) ^ (r & 15);
    __builtin_amdgcn_global_load_lds(
        (const __attribute__((address_space(1))) unsigned int*)(Wt + (size_t)r * 256 + m * 16),
        (__attribute__((address_space(3))) unsigned int*)(lbuf + (8 + wv) * 1024),
        16, 0, 0);
  } else if (wv == 4 && lane < 48) {
    __builtin_amdgcn_global_load_lds(
        (const __attribute__((address_space(1))) unsigned int*)(sgt + lane * 16),
        (__attribute__((address_space(3))) unsigned int*)(lbuf + TILE4B),
        16, 0, 0);
  }
}

// K1: mixed MX MFMA — A = W fp4 (cbsz=4, per-block scales from LDS), B = E fp8.
// R16: T5 s_setprio around the per-tile ds_read+MFMA cluster (2 independent
// blocks/CU provide the phase diversity setprio needs); av high-half zeros
// hoisted. Otherwise byte-identical to verified R15.
__global__ __launch_bounds__(512, 4) void k_main(const unsigned char* __restrict__ Wn4,
                                                 const unsigned char* __restrict__ sigw,
                                                 const unsigned char* __restrict__ En8,
                                                 float* __restrict__ Zp) {
  __shared__ __align__(16) unsigned char wlds[4 * TILESB];   // 52 KB -> 2 blocks/CU
  const int tid  = threadIdx.x;
  const int lane = tid & 63;
  const int wv   = tid >> 6;
  const int g    = lane >> 4;
  const int c    = lane & 15;
  const int rg   = blockIdx.x & (NRG - 1);   // partners share XCD: blk%8 = rg%8
  const int cg   = blockIdx.x >> 7;

  // ---- load this wave's E fragments once: 2 x 4 x i32x8 = 64 VGPRs ----
  i32x8 bfr[NJ][NKQ];
#pragma unroll
  for (int j = 0; j < NJ; ++j) {
    const int col = cg * 256 + wv * 32 + j * 16 + c;
#pragma unroll
    for (int kq = 0; kq < NKQ; ++kq)
      bfr[j][kq] = *reinterpret_cast<const i32x8*>(
          En8 + (size_t)col * DIM + kq * 128 + g * 32);
  }

  float zreg[NJ];
#pragma unroll
  for (int j = 0; j < NJ; ++j) zreg[j] = 0.f;

  // persistent A-operand tuple: high half zeroed ONCE (fp4 A uses low 4 regs)
  i32x8 av;
  av[4] = 0; av[5] = 0; av[6] = 0; av[7] = 0;

  // per-tile compute (verified R14/R15 body + setprio), accumulates into zreg
  auto compute_tile = [&](const unsigned char* lbuf) {
    uint4 sgv[TW];
#pragma unroll
    for (int t = 0; t < TW; ++t)
      sgv[t] = *reinterpret_cast<const uint4*>(lbuf + TILE4B + (t * 16 + c) * 16);

    f32x4 acc[TW][NJ];
#pragma unroll
    for (int t = 0; t < TW; ++t)
#pragma unroll
      for (int j = 0; j < NJ; ++j) acc[t][j] = (f32x4){0.f, 0.f, 0.f, 0.f};

    __builtin_amdgcn_s_setprio(1);
#pragma unroll
    for (int kq = 0; kq < NKQ; ++kq) {
#pragma unroll
      for (int t = 0; t < TW; ++t) {
        const int r = t * 16 + c;                 // r & 15 == c
        const unsigned swd = (&sgv[t].x)[kq];     // static after unroll
        const unsigned sA = ((swd >> (g * 8)) & 0xffu) * 0x01010101u;
        const int s = (kq * 4 + g) ^ c;
        *reinterpret_cast<int4*>(&av) =
            *reinterpret_cast<const int4*>(lbuf + r * 256 + s * 16);
#pragma unroll
        for (int j = 0; j < NJ; ++j)
          acc[t][j] = __builtin_amdgcn_mfma_scale_f32_16x16x128_f8f6f4(
              av, bfr[j][kq], acc[t][j], 4, 0, 0, (int)sA, 0, SCL1);
      }
    }
    __builtin_amdgcn_s_setprio(0);

    // epilogue: sub-center max IN-LANE (permuted rows): max3 + exp
#pragma unroll
    for (int j = 0; j < NJ; ++j) {
      float zc = 0.f;
#pragma unroll
      for (int q = 0; q < 4; ++q) {
        const float mx3 = fmaxf(fmaxf(acc[0][j][q], acc[1][j][q]), acc[2][j][q]);
        zc += eterm(mx3);
      }
      zreg[j] += zc;
    }
  };

  // ---- 4-buffer, 2-tiles-per-barrier pipeline ----
  unsigned char* B0 = wlds;
  unsigned char* B1 = wlds + TILESB;
  unsigned char* B2 = wlds + 2 * TILESB;
  unsigned char* B3 = wlds + 3 * TILESB;

  stage4(Wn4 + (size_t)rg * TILE4B, sigw + (size_t)rg * 768, B0, wv, lane);
  stage4(Wn4 + (size_t)(rg + NRG) * TILE4B, sigw + (size_t)(rg + NRG) * 768, B1, wv, lane);
  __syncthreads();

  for (int t = rg; t < NTILES; t += 2 * NRG) {
    const int t1 = t + NRG, t2 = t + 2 * NRG, t3 = t + 3 * NRG;
    if (t2 < NTILES)
      stage4(Wn4 + (size_t)t2 * TILE4B, sigw + (size_t)t2 * 768, B2, wv, lane);
    if (t3 < NTILES)
      stage4(Wn4 + (size_t)t3 * TILE4B, sigw + (size_t)t3 * 768, B3, wv, lane);

    compute_tile(B0);
    if (t1 < NTILES) compute_tile(B1);

    __syncthreads();   // readers done with B0/B1 + B2/B3 stages drained
    unsigned char* x;
    x = B0; B0 = B2; B2 = x;
    x = B1; B1 = B3; B3 = x;
  }

  // ---- final cross-lane reduction ----
#pragma unroll
  for (int j = 0; j < NJ; ++j) {
    zreg[j] += __shfl_xor(zreg[j], 16, 64);
    zreg[j] += __shfl_xor(zreg[j], 32, 64);
  }
  if (g == 0) {
#pragma unroll
    for (int j = 0; j < NJ; ++j)
      Zp[(size_t)rg * BQ + cg * 256 + wv * 32 + j * 16 + c] = zreg[j];
  }
}

// K3: Z[b] = sum over 128 row-group partials; per-row loss; block partial sums
__global__ __launch_bounds__(256) void k_reduce(const float* __restrict__ Zp,
                                                const float* __restrict__ delta,
                                                const float* __restrict__ tl,
                                                float* __restrict__ part) {
  const int b = blockIdx.x * 256 + threadIdx.x;
  float z = 0.f;
#pragma unroll 8
  for (int nb = 0; nb < NRG; ++nb) z += Zp[(size_t)nb * BQ + b];
  float lossb = logf(z + delta[b]) - tl[b];
  __shared__ float sm[256];
  sm[threadIdx.x] = lossb;
  __syncthreads();
#pragma unroll
  for (int s = 128; s > 0; s >>= 1) {
    if (threadIdx.x < s) sm[threadIdx.x] += sm[threadIdx.x + s];
    __syncthreads();
  }
  if (threadIdx.x == 0) part[blockIdx.x] = sm[0];
}

__global__ void k_final(const float* __restrict__ part, float* __restrict__ out) {
  out[0] = (part[0] + part[1] + part[2] + part[3]) * (1.0f / BQ);
}

extern "C" void kernel_launch(void* const* d_in, const int* in_sizes, int n_in,
                              void* d_out, int out_size, void* d_ws, size_t ws_size,
                              hipStream_t stream) {
  const float* E  = (const float*)d_in[0];
  const int* lab  = (const int*)d_in[1];
  const float* W  = (const float*)d_in[2];

  char* ws = (char*)d_ws;
  unsigned char* En8 = (unsigned char*)ws;                            // 512 KB
  unsigned char* Wn4 = (unsigned char*)(ws + (size_t)BQ * DIM);       // 38.4 MB
  unsigned* sigw = (unsigned*)(ws + (size_t)BQ * DIM + (size_t)NROWSW * 256);  // 2.4 MB
  char* after = (char*)(sigw + (size_t)NROWSW * 4);
  float* Zp    = (float*)after;                                       // 512 KB
  float* delta = Zp + (size_t)NRG * BQ;
  float* tl    = delta + BQ;
  float* part  = tl + BQ;

  hipLaunchKernelGGL(k_prenorm, dim3(NROWSW / 4), dim3(256), 0, stream, W, Wn4, sigw);
  hipLaunchKernelGGL(k_prep,    dim3(BQ),         dim3(64),  0, stream, E, lab, W, En8, delta, tl);
  hipLaunchKernelGGL(k_main,    dim3(NRG * NCG),  dim3(512), 0, stream, Wn4, (unsigned char*)sigw, En8, Zp);
  hipLaunchKernelGGL(k_reduce,  dim3(4),          dim3(256), 0, stream, Zp, delta, tl, part);
  hipLaunchKernelGGL(k_final,   dim3(1),          dim3(1),   0, stream, part, (float*)d_out);
}